// Round 16
// baseline (58.432 us; speedup 1.0000x reference)
//
#include <hip/hip_runtime.h>

// Chamfer via MFMA, 32x32x16 (layout verified exact in R15): d[n,m] =
// na + nb - 2 a.b, 13-slot K packing:
//   k 0-2: ah*(-2bh)  k 3-5: ah*(-2bl)  k 6-8: al*(-2bh)
//   k 9,10: nah,nal * 1   k 11,12: 1 * nbh,nbl   k 13-15: zero
// A-frag: lane holds A[row=lane&31][k=(lane>>5)*8+e]; B-frag symmetric;
// C/D: col=lane&31, row=(reg&3)+8*(reg>>2)+4*(lane>>5)  [m74/m101].
// Each matrix computed ONCE: row-mins -> d1/p1, col-mins -> d2/p2.
// R16 change vs R15: NO cT LDS table -- per-t col-min goes straight to the
// global atomicMin from lanes<32 (one barrier total, LDS=24KB -> 6 blk/CU).
// 2048 uniform blocks x 256 thr; block = 256 rows x 512 cols; wave = 2
// row-panels of 32 x 16 col-tiles of 32. Row-mins: width-32 shfl tree.
// atomicMin monotone-key table (exact, order-independent); 0xFF init in prep.

#define N2K 2048
#define N8K 8192
#define THREADS 256

// ws u32 layout:
#define D1_BASE 0          // d1: b*8192+a
#define D2_BASE 65536      // d2: b*2048+a
#define P1_BASE 81920      // p1: b*8192+p*2048+a
#define P2_BASE 147456     // p2: b*8192+p*2048+a
#define NMINS 212992
#define PART_BASE 212992   // 208 floats
#define RV_BASE 213504     // data row-vecs : 65536 pts x 8 u32 (32B)
#define CR_BASE 737792     // rec  col-vecs : 16384 pts x 8 u32
#define CP_BASE 868864     // recp col-vecs : 65536 pts x 8 u32  (end 1393152)

typedef short bf16x8 __attribute__((ext_vector_type(8)));
typedef float f32x16 __attribute__((ext_vector_type(16)));

__device__ __forceinline__ float min3f(float a, float b, float c) {
    float d;
    asm("v_min3_f32 %0, %1, %2, %3" : "=v"(d) : "v"(a), "v"(b), "v"(c));
    return d;
}
__device__ __forceinline__ unsigned int fkey(float v) {
    unsigned int u = __float_as_uint(v);
    return (u & 0x80000000u) ? ~u : (u | 0x80000000u);
}
__device__ __forceinline__ unsigned short bf16rne(float f) {
    unsigned int u = __float_as_uint(f);
    return (unsigned short)((u + 0x7FFFu + ((u >> 16) & 1u)) >> 16);
}
__device__ __forceinline__ float bf2f(unsigned short s) {
    return __uint_as_float(((unsigned int)s) << 16);
}
// min over 16 regs of a C/D frag (8-op min3 tree)
__device__ __forceinline__ float min16(f32x16 d) {
    float v = min3f(d[0], d[1], d[2]);
    v = min3f(v, d[3], d[4]);
    v = min3f(v, d[5], d[6]);
    v = min3f(v, d[7], d[8]);
    v = min3f(v, d[9], d[10]);
    v = min3f(v, d[11], d[12]);
    v = min3f(v, d[13], d[14]);
    return fminf(v, d[15]);
}

__global__ __launch_bounds__(THREADS) void prep_kernel(
    const float* __restrict__ data, const float* __restrict__ rec,
    const float* __restrict__ recp, unsigned int* __restrict__ ws)
{
    const int idx = blockIdx.x * THREADS + threadIdx.x;   // 0..147455

    // fused min-table init (replaces hipMemsetAsync): [0, NMINS) <- 0xFF..
    if (idx < NMINS) ws[idx] = 0xFFFFFFFFu;
    if (idx + 147456 < NMINS) ws[idx + 147456] = 0xFFFFFFFFu;

    float x, y, z; int out; int isrow;
    if (idx < 65536) {                       // data -> row vectors
        int b = idx >> 13, i = idx & 8191;
        const float* p = data + b * 3 * N8K;
        x = p[i]; y = p[N8K + i]; z = p[2 * N8K + i];
        out = RV_BASE + idx * 8; isrow = 1;
    } else if (idx < 81920) {                // rec -> col vectors
        int j = idx - 65536; int b = j >> 11, i = j & 2047;
        const float* p = rec + b * 3 * N2K;
        x = p[i]; y = p[N2K + i]; z = p[2 * N2K + i];
        out = CR_BASE + j * 8; isrow = 0;
    } else {                                 // recp -> col vectors
        int j = idx - 81920; int b = j >> 13, i = j & 8191;
        const float* p = recp + b * 3 * N8K;
        x = p[i]; y = p[N8K + i]; z = p[2 * N8K + i];
        out = CP_BASE + j * 8; isrow = 0;
    }
    unsigned short xh = bf16rne(x), yh = bf16rne(y), zh = bf16rne(z);
    unsigned short xl = bf16rne(x - bf2f(xh));
    unsigned short yl = bf16rne(y - bf2f(yh));
    unsigned short zl = bf16rne(z - bf2f(zh));
    float na = x * x + y * y + z * z;
    unsigned short nh = bf16rne(na);
    unsigned short nl = bf16rne(na - bf2f(nh));
    const unsigned short ONE = 0x3F80u;
    unsigned short s[16];
    if (isrow) {
        s[0]=xh; s[1]=yh; s[2]=zh;  s[3]=xh; s[4]=yh; s[5]=zh;
        s[6]=xl; s[7]=yl; s[8]=zl;  s[9]=nh; s[10]=nl;
        s[11]=ONE; s[12]=ONE; s[13]=0; s[14]=0; s[15]=0;
    } else {
        unsigned short m2xh = bf16rne(-2.f * bf2f(xh));
        unsigned short m2yh = bf16rne(-2.f * bf2f(yh));
        unsigned short m2zh = bf16rne(-2.f * bf2f(zh));
        unsigned short m2xl = bf16rne(-2.f * bf2f(xl));
        unsigned short m2yl = bf16rne(-2.f * bf2f(yl));
        unsigned short m2zl = bf16rne(-2.f * bf2f(zl));
        s[0]=m2xh; s[1]=m2yh; s[2]=m2zh;  s[3]=m2xl; s[4]=m2yl; s[5]=m2zl;
        s[6]=m2xh; s[7]=m2yh; s[8]=m2zh;  s[9]=ONE; s[10]=ONE;
        s[11]=nh; s[12]=nl; s[13]=0; s[14]=0; s[15]=0;
    }
    uint4 w0, w1;
    w0.x = (unsigned)s[0]  | ((unsigned)s[1]  << 16);
    w0.y = (unsigned)s[2]  | ((unsigned)s[3]  << 16);
    w0.z = (unsigned)s[4]  | ((unsigned)s[5]  << 16);
    w0.w = (unsigned)s[6]  | ((unsigned)s[7]  << 16);
    w1.x = (unsigned)s[8]  | ((unsigned)s[9]  << 16);
    w1.y = (unsigned)s[10] | ((unsigned)s[11] << 16);
    w1.z = (unsigned)s[12] | ((unsigned)s[13] << 16);
    w1.w = (unsigned)s[14] | ((unsigned)s[15] << 16);
    uint4* dst = (uint4*)(ws + out);
    dst[0] = w0; dst[1] = w1;
}

__global__ __launch_bounds__(THREADS) void mfma_chamfer_kernel(unsigned int* ws)
{
    __shared__ unsigned int sB[512 * 12];   // col-vecs, 48B stride (24 KB)

    const int tid = threadIdx.x, lane = tid & 63, wv = tid >> 6;
    const int hi = lane >> 5, col = lane & 31;
    const int bid = blockIdx.x;             // 2048 blocks

    int rvec, cvec, rowTab, colTab;
    if (bid < 1024) {       // G: data(rows) x rec(cols); 8b x 32rp x 4mh
        int b = bid >> 7, rp = (bid >> 2) & 31, mh = bid & 3;
        rvec = RV_BASE + (b * N8K + rp * 256) * 8;
        cvec = CR_BASE + (b * N2K + mh * 512) * 8;
        rowTab = D1_BASE + b * N8K + rp * 256;
        colTab = D2_BASE + b * N2K + mh * 512;
    } else {                // P: dataseg x recpseg; 32bp x 8rq x 4mh
        int j = bid - 1024, bp = j >> 5, rq = (j >> 2) & 7, mh = j & 3;
        int b = bp >> 2, p = bp & 3;
        rvec = RV_BASE + (b * N8K + p * N2K + rq * 256) * 8;
        cvec = CP_BASE + (b * N8K + p * N2K + mh * 512) * 8;
        rowTab = P1_BASE + b * N8K + p * N2K + rq * 256;
        colTab = P2_BASE + b * N8K + p * N2K + mh * 512;
    }

    // stage 512 col-vecs into LDS (2 x uint4 per point, stride 12 u32)
    {
        const uint4* src = (const uint4*)(ws + cvec);
        for (int pt = tid; pt < 512; pt += THREADS) {
            uint4 w0 = src[pt * 2], w1 = src[pt * 2 + 1];
            unsigned int* dst = sB + pt * 12;
            *(uint4*)dst = w0;
            *(uint4*)(dst + 4) = w1;
        }
    }

    const char* base = (const char*)ws;
    const f32x16 zacc = {0.f,0.f,0.f,0.f, 0.f,0.f,0.f,0.f,
                         0.f,0.f,0.f,0.f, 0.f,0.f,0.f,0.f};

    // A-frags: 2 row-panels of 32; lane holds A[row][k=hi*8+e] (16B load)
    const int row0 = wv * 64 + col;
    bf16x8 afr0 = *(const bf16x8*)(base + (size_t)(rvec + row0 * 8) * 4 + hi * 16);
    bf16x8 afr1 = *(const bf16x8*)(base + (size_t)(rvec + (row0 + 32) * 8) * 4 + hi * 16);

    float rm0[16], rm1[16];
    #pragma unroll
    for (int r = 0; r < 16; ++r) { rm0[r] = 3.4e38f; rm1[r] = 3.4e38f; }

    __syncthreads();

    unsigned int* mins = ws;

    #pragma unroll 2
    for (int t = 0; t < 16; ++t) {
        bf16x8 bu = *(const bf16x8*)((const char*)sB + (t * 32 + col) * 48 + hi * 16);
        f32x16 d0 = __builtin_amdgcn_mfma_f32_32x32x16_bf16(afr0, bu, zacc, 0, 0, 0);
        f32x16 d1 = __builtin_amdgcn_mfma_f32_32x32x16_bf16(afr1, bu, zacc, 0, 0, 0);
        #pragma unroll
        for (int r = 0; r < 16; ++r) {
            rm0[r] = fminf(rm0[r], d0[r]);
            rm1[r] = fminf(rm1[r], d1[r]);
        }
        float v = fminf(min16(d0), min16(d1));       // col-min, this wave's rows
        v = fminf(v, __shfl_xor(v, 32, 64));         // merge hi/lo row groups
        if (lane < 32)
            atomicMin(&mins[colTab + t * 32 + col], fkey(v));   // direct, no cT
    }

    // row-mins: reduce across the 32 col-lanes (width-32 xor tree)
    #pragma unroll
    for (int pr = 0; pr < 32; ++pr) {
        const int p = pr >> 4, r = pr & 15;
        float v = p ? rm1[r] : rm0[r];
        v = fminf(v, __shfl_xor(v, 1, 32));
        v = fminf(v, __shfl_xor(v, 2, 32));
        v = fminf(v, __shfl_xor(v, 4, 32));
        v = fminf(v, __shfl_xor(v, 8, 32));
        v = fminf(v, __shfl_xor(v, 16, 32));
        if (col == 0) {
            int row = wv * 64 + p * 32 + (r & 3) + 8 * (r >> 2) + 4 * hi;
            atomicMin(&mins[rowTab + row], fkey(v));
        }
    }
}

__global__ __launch_bounds__(THREADS) void finalize1_kernel(
    const unsigned int* __restrict__ mins, float* __restrict__ part)
{
    __shared__ float sred[4];
    const int blk = blockIdx.x;        // 208 blocks x 1024 entries
    const int tid = threadIdx.x;

    float s = 0.f;
    #pragma unroll
    for (int i = 0; i < 4; ++i) {
        int idx = blk * 1024 + i * THREADS + tid;
        unsigned int k = mins[idx];
        unsigned int bu = (k & 0x80000000u) ? (k & 0x7FFFFFFFu) : ~k;
        float v = __uint_as_float(bu);
        float w = (idx < 65536) ? (1.f / 65536.f) : (1.f / 16384.f);
        s += v * w;
    }
    #pragma unroll
    for (int o = 32; o > 0; o >>= 1) s += __shfl_down(s, o, 64);
    const int lane = tid & 63, wid = tid >> 6;
    if (lane == 0) sred[wid] = s;
    __syncthreads();
    if (tid == 0)
        part[blk] = (sred[0] + sred[1]) + (sred[2] + sred[3]);
}

__global__ __launch_bounds__(THREADS) void finalize2_kernel(
    const float* __restrict__ part, float* __restrict__ out)
{
    __shared__ float sred[4];
    const int tid = threadIdx.x;
    float s = (tid < 208) ? part[tid] : 0.f;
    #pragma unroll
    for (int o = 32; o > 0; o >>= 1) s += __shfl_down(s, o, 64);
    const int lane = tid & 63, wid = tid >> 6;
    if (lane == 0) sred[wid] = s;
    __syncthreads();
    if (tid == 0)
        out[0] = ((sred[0] + sred[1]) + (sred[2] + sred[3])) * 0.2f;  // /5
}

extern "C" void kernel_launch(void* const* d_in, const int* in_sizes, int n_in,
                              void* d_out, int out_size, void* d_ws, size_t ws_size,
                              hipStream_t stream) {
    const float* data = (const float*)d_in[0];
    const float* rec  = (const float*)d_in[1];
    const float* recp = (const float*)d_in[2];
    float* out = (float*)d_out;
    unsigned int* ws = (unsigned int*)d_ws;
    float* part = (float*)d_ws + PART_BASE;

    prep_kernel<<<576, THREADS, 0, stream>>>(data, rec, recp, ws);
    mfma_chamfer_kernel<<<2048, THREADS, 0, stream>>>(ws);
    finalize1_kernel<<<208, THREADS, 0, stream>>>(ws, part);
    finalize2_kernel<<<1, THREADS, 0, stream>>>(part, out);
}

// Round 17
// 53.440 us; speedup vs baseline: 1.0934x; 1.0934x over previous
//
#include <hip/hip_runtime.h>

// Chamfer via MFMA (16x16x32, R14 structure — best measured) with INLINE
// vector prep (no prep kernel, no ws vector round-trip).
// d[n,m] = na + nb - 2 a.b via 13-slot K packing (verified exact R11-R16):
//   row slots: [xh,yh,zh, xh,yh,zh, xl,yl | zl, nh,nl, 1,1, 0,0,0]
//   col slots: [-2xh,-2yh,-2zh, -2xl,-2yl,-2zl, -2xh,-2yh | -2zh, 1,1,
//               nbh,nbl, 0,0,0]   (g>=2 lanes carry zero frags)
// Matrix computed ONCE: row-mins -> d1/p1, col-mins -> d2/p2.
// 1024 blocks x 256 thr; block = 512 rows x 512 cols; per-t col-min ->
// cT[wave][col][g], two halves of 16 t, merge + 1 atomic/col per half.
// s_setprio(1) around MFMA batch (T5). atomicMin monotone-key table
// (exact, order-independent -> deterministic); 0xFF init via memsetAsync.

#define N2K 2048
#define N8K 8192
#define THREADS 256

// ws u32 layout: min table + partials only
#define D1_BASE 0          // d1: b*8192+a
#define D2_BASE 65536      // d2: b*2048+a
#define P1_BASE 81920      // p1: b*8192+p*2048+a
#define P2_BASE 147456     // p2: b*8192+p*2048+a
#define NMINS 212992
#define PART_BASE 212992   // 208 floats

typedef short bf16x8 __attribute__((ext_vector_type(8)));
typedef float f32x4 __attribute__((ext_vector_type(4)));

__device__ __forceinline__ float min3f(float a, float b, float c) {
    float d;
    asm("v_min3_f32 %0, %1, %2, %3" : "=v"(d) : "v"(a), "v"(b), "v"(c));
    return d;
}
__device__ __forceinline__ unsigned int fkey(float v) {
    unsigned int u = __float_as_uint(v);
    return (u & 0x80000000u) ? ~u : (u | 0x80000000u);
}
__device__ __forceinline__ unsigned short bf16rne(float f) {
    unsigned int u = __float_as_uint(f);
    return (unsigned short)((u + 0x7FFFu + ((u >> 16) & 1u)) >> 16);
}
__device__ __forceinline__ float bf2f(unsigned short s) {
    return __uint_as_float(((unsigned int)s) << 16);
}

__global__ __launch_bounds__(THREADS) void mfma_chamfer_kernel(
    const float* __restrict__ data, const float* __restrict__ rec,
    const float* __restrict__ recp, unsigned int* __restrict__ mins)
{
    __shared__ unsigned int sB[512 * 12];   // col-vecs, 48B stride (24 KB)
    __shared__ float cT[4][256][4];         // [wave][col_local][g] (16 KB)

    const int tid = threadIdx.x, lane = tid & 63, wv = tid >> 6;
    const int g = lane >> 4, rln = lane & 15;
    const int bid = blockIdx.x;             // 1024 blocks

    const float* Rb; int rowbase;           // rows always from data[b]
    const float* Cb; int Cs; int colbase;
    int rowTab, colTab;
    if (bid < 512) {        // G: data(rows) x rec(cols); 8b x 16rp x 4mh
        int b = bid >> 6, rp = (bid >> 2) & 15, mh = bid & 3;
        Rb = data + b * 3 * N8K; rowbase = rp * 512;
        Cb = rec  + b * 3 * N2K; Cs = N2K; colbase = mh * 512;
        rowTab = D1_BASE + b * N8K + rp * 512;
        colTab = D2_BASE + b * N2K + mh * 512;
    } else {                // P: dataseg x recpseg; 32bp x 4rq x 4mh
        int j = bid - 512, bp = j >> 4, rq = (j >> 2) & 3, mh = j & 3;
        int b = bp >> 2, p = bp & 3;
        Rb = data + b * 3 * N8K; rowbase = p * N2K + rq * 512;
        Cb = recp + b * 3 * N8K; Cs = N8K; colbase = p * N2K + mh * 512;
        rowTab = P1_BASE + b * N8K + p * N2K + rq * 512;
        colTab = P2_BASE + b * N8K + p * N2K + mh * 512;
    }

    // ---- inline col prep: 512 pts, 2 per thread, packed to sB ----
    for (int k = tid; k < 512; k += THREADS) {
        int co = colbase + k;
        float x = Cb[co], y = Cb[Cs + co], z = Cb[2 * Cs + co];
        unsigned short xh = bf16rne(x), yh = bf16rne(y), zh = bf16rne(z);
        unsigned short xl = bf16rne(x - bf2f(xh));
        unsigned short yl = bf16rne(y - bf2f(yh));
        unsigned short zl = bf16rne(z - bf2f(zh));
        float nb = x * x + y * y + z * z;
        unsigned short nh = bf16rne(nb);
        unsigned short nl = bf16rne(nb - bf2f(nh));
        unsigned short m2xh = bf16rne(-2.f * bf2f(xh));
        unsigned short m2yh = bf16rne(-2.f * bf2f(yh));
        unsigned short m2zh = bf16rne(-2.f * bf2f(zh));
        unsigned short m2xl = bf16rne(-2.f * bf2f(xl));
        unsigned short m2yl = bf16rne(-2.f * bf2f(yl));
        unsigned short m2zl = bf16rne(-2.f * bf2f(zl));
        const unsigned short ONE = 0x3F80u;
        unsigned int* dst = sB + k * 12;
        uint4 w0, w1;
        w0.x = (unsigned)m2xh | ((unsigned)m2yh << 16);
        w0.y = (unsigned)m2zh | ((unsigned)m2xl << 16);
        w0.z = (unsigned)m2yl | ((unsigned)m2zl << 16);
        w0.w = (unsigned)m2xh | ((unsigned)m2yh << 16);
        w1.x = (unsigned)m2zh | ((unsigned)ONE  << 16);
        w1.y = (unsigned)ONE  | ((unsigned)nh   << 16);
        w1.z = (unsigned)nl;          // slot13 zero
        w1.w = 0;                     // slots 14,15 zero
        *(uint4*)dst = w0;
        *(uint4*)(dst + 4) = w1;
    }

    // ---- inline row prep: A-frags for 8 panels (g<2 lanes only) ----
    const bf16x8 zero8 = {0, 0, 0, 0, 0, 0, 0, 0};
    const f32x4 zacc = {0.f, 0.f, 0.f, 0.f};
    bf16x8 afr[8];
    #pragma unroll
    for (int p = 0; p < 8; ++p) {
        if (g < 2) {
            int ro = rowbase + wv * 128 + p * 16 + rln;
            float x = Rb[ro], y = Rb[N8K + ro], z = Rb[2 * N8K + ro];
            unsigned short xh = bf16rne(x), yh = bf16rne(y), zh = bf16rne(z);
            unsigned short xl = bf16rne(x - bf2f(xh));
            unsigned short yl = bf16rne(y - bf2f(yh));
            unsigned short zl = bf16rne(z - bf2f(zh));
            float na = x * x + y * y + z * z;
            unsigned short nh = bf16rne(na);
            unsigned short nl = bf16rne(na - bf2f(nh));
            const unsigned short ONE = 0x3F80u;
            bf16x8 f;
            if (g == 0) {
                f[0] = (short)xh; f[1] = (short)yh; f[2] = (short)zh;
                f[3] = (short)xh; f[4] = (short)yh; f[5] = (short)zh;
                f[6] = (short)xl; f[7] = (short)yl;
            } else {
                f[0] = (short)zl; f[1] = (short)nh; f[2] = (short)nl;
                f[3] = (short)ONE; f[4] = (short)ONE;
                f[5] = 0; f[6] = 0; f[7] = 0;
            }
            afr[p] = f;
        } else {
            afr[p] = zero8;
        }
    }

    float rm[8][4];
    #pragma unroll
    for (int p = 0; p < 8; ++p) {
        rm[p][0] = 3.4e38f; rm[p][1] = 3.4e38f;
        rm[p][2] = 3.4e38f; rm[p][3] = 3.4e38f;
    }

    __syncthreads();

    #pragma unroll 1
    for (int half = 0; half < 2; ++half) {
        #pragma unroll 2
        for (int tt = 0; tt < 16; ++tt) {
            const int t = half * 16 + tt;
            bf16x8 bu = zero8;
            if (g < 2)
                bu = *(const bf16x8*)((const char*)sB + (t * 16 + rln) * 48 + g * 16);
            f32x4 d[8];
            __builtin_amdgcn_s_setprio(1);
            #pragma unroll
            for (int p = 0; p < 8; ++p)
                d[p] = __builtin_amdgcn_mfma_f32_16x16x32_bf16(afr[p], bu, zacc, 0, 0, 0);
            __builtin_amdgcn_s_setprio(0);
            float cmt = 3.4e38f;
            #pragma unroll
            for (int p = 0; p < 8; ++p) {
                rm[p][0] = fminf(rm[p][0], d[p][0]);
                rm[p][1] = fminf(rm[p][1], d[p][1]);
                rm[p][2] = fminf(rm[p][2], d[p][2]);
                rm[p][3] = fminf(rm[p][3], d[p][3]);
                float w = min3f(d[p][1], d[p][2], d[p][3]);   // indep per p
                cmt = min3f(cmt, d[p][0], w);                 // 8-deep chain
            }
            cT[wv][tt * 16 + rln][g] = cmt;    // unique slot, no conflicts
        }
        __syncthreads();
        // merge: 256 threads x 256 local cols; min over 4 waves x 4 g
        {
            float4 q0 = *(const float4*)&cT[0][tid][0];
            float4 q1 = *(const float4*)&cT[1][tid][0];
            float4 q2 = *(const float4*)&cT[2][tid][0];
            float4 q3 = *(const float4*)&cT[3][tid][0];
            float v = fminf(fminf(fminf(q0.x, q0.y), fminf(q0.z, q0.w)),
                            fminf(fminf(q1.x, q1.y), fminf(q1.z, q1.w)));
            v = fminf(v, fminf(fminf(q2.x, q2.y), fminf(q2.z, q2.w)));
            v = fminf(v, fminf(fminf(q3.x, q3.y), fminf(q3.z, q3.w)));
            atomicMin(&mins[colTab + half * 256 + tid], fkey(v));
        }
        __syncthreads();
    }

    // row-mins: reduce across 16 col-lanes (xor 1,2,4,8), one atomic per row
    #pragma unroll
    for (int p = 0; p < 8; ++p) {
        #pragma unroll
        for (int q = 0; q < 4; ++q) {
            float v = rm[p][q];
            v = fminf(v, __shfl_xor(v, 1, 64));
            v = fminf(v, __shfl_xor(v, 2, 64));
            v = fminf(v, __shfl_xor(v, 4, 64));
            v = fminf(v, __shfl_xor(v, 8, 64));
            if (rln == 0)
                atomicMin(&mins[rowTab + wv * 128 + p * 16 + g * 4 + q], fkey(v));
        }
    }
}

__global__ __launch_bounds__(THREADS) void finalize1_kernel(
    const unsigned int* __restrict__ mins, float* __restrict__ part)
{
    __shared__ float sred[4];
    const int blk = blockIdx.x;        // 208 blocks x 1024 entries
    const int tid = threadIdx.x;

    float s = 0.f;
    #pragma unroll
    for (int i = 0; i < 4; ++i) {
        int idx = blk * 1024 + i * THREADS + tid;
        unsigned int k = mins[idx];
        unsigned int bu = (k & 0x80000000u) ? (k & 0x7FFFFFFFu) : ~k;
        float v = __uint_as_float(bu);
        float w = (idx < 65536) ? (1.f / 65536.f) : (1.f / 16384.f);
        s += v * w;
    }
    #pragma unroll
    for (int o = 32; o > 0; o >>= 1) s += __shfl_down(s, o, 64);
    const int lane = tid & 63, wid = tid >> 6;
    if (lane == 0) sred[wid] = s;
    __syncthreads();
    if (tid == 0)
        part[blk] = (sred[0] + sred[1]) + (sred[2] + sred[3]);
}

__global__ __launch_bounds__(THREADS) void finalize2_kernel(
    const float* __restrict__ part, float* __restrict__ out)
{
    __shared__ float sred[4];
    const int tid = threadIdx.x;
    float s = (tid < 208) ? part[tid] : 0.f;
    #pragma unroll
    for (int o = 32; o > 0; o >>= 1) s += __shfl_down(s, o, 64);
    const int lane = tid & 63, wid = tid >> 6;
    if (lane == 0) sred[wid] = s;
    __syncthreads();
    if (tid == 0)
        out[0] = ((sred[0] + sred[1]) + (sred[2] + sred[3])) * 0.2f;  // /5
}

extern "C" void kernel_launch(void* const* d_in, const int* in_sizes, int n_in,
                              void* d_out, int out_size, void* d_ws, size_t ws_size,
                              hipStream_t stream) {
    const float* data = (const float*)d_in[0];
    const float* rec  = (const float*)d_in[1];
    const float* recp = (const float*)d_in[2];
    float* out = (float*)d_out;
    unsigned int* mins = (unsigned int*)d_ws;
    float* part = (float*)d_ws + PART_BASE;

    // init min table to key-max (0xFFFFFFFF > any real key)
    hipMemsetAsync(d_ws, 0xFF, NMINS * sizeof(unsigned int), stream);
    mfma_chamfer_kernel<<<1024, THREADS, 0, stream>>>(data, rec, recp, mins);
    finalize1_kernel<<<208, THREADS, 0, stream>>>(mins, part);
    finalize2_kernel<<<1, THREADS, 0, stream>>>(part, out);
}

// Round 19
// 51.594 us; speedup vs baseline: 1.1325x; 1.0358x over previous
//
#include <hip/hip_runtime.h>

// Chamfer via MFMA — R14 structure + R18 depth-cuts, NaN-fixed:
//  (1) bu ds_read UNGUARDED — now SAFE: staging zero-fills bytes 32..47 of
//      every 48B record (the R18 NaN source was uninitialized LDS there),
//      so g=2 reads zeros, g=3 reads next record's finite coords, and the
//      final record's g=3 read lands in the 4-word zero pad.
//  (2) col-min as a tree (depth ~2 min3 levels) instead of 8-deep chain.
//  (3) s_setprio(1) around the 8-MFMA batch (T5).
// Math (verified exact R11-R17): d = na + nb - 2 a.b, 13-slot K packing:
//   k0-2: ah*(-2bh)  k3-5: ah*(-2bl)  k6-8: al*(-2bh)
//   k9,10: nah,nal*1  k11,12: 1*nbh,nbl  k>=13: zero (A-side g>=2 zero)
// Matrix computed ONCE: row-mins -> d1/p1, col-mins -> d2/p2. atomicMin
// monotone-key table (exact, order-independent -> deterministic).

#define N2K 2048
#define N8K 8192
#define THREADS 256

// ws u32 layout:
#define D1_BASE 0          // d1: b*8192+a
#define D2_BASE 65536      // d2: b*2048+a
#define P1_BASE 81920      // p1: b*8192+p*2048+a
#define P2_BASE 147456     // p2: b*8192+p*2048+a
#define NMINS 212992
#define PART_BASE 212992   // 208 floats
#define RV_BASE 213504     // data row-vecs : 65536 pts x 8 u32 (32B)
#define CR_BASE 737792     // rec  col-vecs : 16384 pts x 8 u32
#define CP_BASE 868864     // recp col-vecs : 65536 pts x 8 u32  (end 1393152)

typedef short bf16x8 __attribute__((ext_vector_type(8)));
typedef float f32x4 __attribute__((ext_vector_type(4)));

__device__ __forceinline__ float min3f(float a, float b, float c) {
    float d;
    asm("v_min3_f32 %0, %1, %2, %3" : "=v"(d) : "v"(a), "v"(b), "v"(c));
    return d;
}
__device__ __forceinline__ unsigned int fkey(float v) {
    unsigned int u = __float_as_uint(v);
    return (u & 0x80000000u) ? ~u : (u | 0x80000000u);
}
__device__ __forceinline__ unsigned short bf16rne(float f) {
    unsigned int u = __float_as_uint(f);
    return (unsigned short)((u + 0x7FFFu + ((u >> 16) & 1u)) >> 16);
}
__device__ __forceinline__ float bf2f(unsigned short s) {
    return __uint_as_float(((unsigned int)s) << 16);
}

__global__ __launch_bounds__(THREADS) void prep_kernel(
    const float* __restrict__ data, const float* __restrict__ rec,
    const float* __restrict__ recp, unsigned int* __restrict__ ws)
{
    const int idx = blockIdx.x * THREADS + threadIdx.x;   // 0..147455

    // fused min-table init: [0, NMINS) <- 0xFF..
    if (idx < NMINS) ws[idx] = 0xFFFFFFFFu;
    if (idx + 147456 < NMINS) ws[idx + 147456] = 0xFFFFFFFFu;

    float x, y, z; int out; int isrow;
    if (idx < 65536) {                       // data -> row vectors
        int b = idx >> 13, i = idx & 8191;
        const float* p = data + b * 3 * N8K;
        x = p[i]; y = p[N8K + i]; z = p[2 * N8K + i];
        out = RV_BASE + idx * 8; isrow = 1;
    } else if (idx < 81920) {                // rec -> col vectors
        int j = idx - 65536; int b = j >> 11, i = j & 2047;
        const float* p = rec + b * 3 * N2K;
        x = p[i]; y = p[N2K + i]; z = p[2 * N2K + i];
        out = CR_BASE + j * 8; isrow = 0;
    } else {                                 // recp -> col vectors
        int j = idx - 81920; int b = j >> 13, i = j & 8191;
        const float* p = recp + b * 3 * N8K;
        x = p[i]; y = p[N8K + i]; z = p[2 * N8K + i];
        out = CP_BASE + j * 8; isrow = 0;
    }
    unsigned short xh = bf16rne(x), yh = bf16rne(y), zh = bf16rne(z);
    unsigned short xl = bf16rne(x - bf2f(xh));
    unsigned short yl = bf16rne(y - bf2f(yh));
    unsigned short zl = bf16rne(z - bf2f(zh));
    float na = x * x + y * y + z * z;
    unsigned short nh = bf16rne(na);
    unsigned short nl = bf16rne(na - bf2f(nh));
    const unsigned short ONE = 0x3F80u;
    unsigned short s[16];
    if (isrow) {
        s[0]=xh; s[1]=yh; s[2]=zh;  s[3]=xh; s[4]=yh; s[5]=zh;
        s[6]=xl; s[7]=yl; s[8]=zl;  s[9]=nh; s[10]=nl;
        s[11]=ONE; s[12]=ONE; s[13]=0; s[14]=0; s[15]=0;
    } else {
        unsigned short m2xh = bf16rne(-2.f * bf2f(xh));
        unsigned short m2yh = bf16rne(-2.f * bf2f(yh));
        unsigned short m2zh = bf16rne(-2.f * bf2f(zh));
        unsigned short m2xl = bf16rne(-2.f * bf2f(xl));
        unsigned short m2yl = bf16rne(-2.f * bf2f(yl));
        unsigned short m2zl = bf16rne(-2.f * bf2f(zl));
        s[0]=m2xh; s[1]=m2yh; s[2]=m2zh;  s[3]=m2xl; s[4]=m2yl; s[5]=m2zl;
        s[6]=m2xh; s[7]=m2yh; s[8]=m2zh;  s[9]=ONE; s[10]=ONE;
        s[11]=nh; s[12]=nl; s[13]=0; s[14]=0; s[15]=0;
    }
    uint4 w0, w1;
    w0.x = (unsigned)s[0]  | ((unsigned)s[1]  << 16);
    w0.y = (unsigned)s[2]  | ((unsigned)s[3]  << 16);
    w0.z = (unsigned)s[4]  | ((unsigned)s[5]  << 16);
    w0.w = (unsigned)s[6]  | ((unsigned)s[7]  << 16);
    w1.x = (unsigned)s[8]  | ((unsigned)s[9]  << 16);
    w1.y = (unsigned)s[10] | ((unsigned)s[11] << 16);
    w1.z = (unsigned)s[12] | ((unsigned)s[13] << 16);
    w1.w = (unsigned)s[14] | ((unsigned)s[15] << 16);
    uint4* dst = (uint4*)(ws + out);
    dst[0] = w0; dst[1] = w1;
}

__global__ __launch_bounds__(THREADS) void mfma_chamfer_kernel(unsigned int* ws)
{
    __shared__ unsigned int sB[512 * 12 + 4];  // +4 zero pad for unguarded read
    __shared__ float cT[4][256][4];            // [wave][col_local][g] (16 KB)

    const int tid = threadIdx.x, lane = tid & 63, wv = tid >> 6;
    const int g = lane >> 4, rln = lane & 15;
    const int bid = blockIdx.x;             // 1024 blocks

    int rvec, cvec, rowTab, colTab;
    if (bid < 512) {        // G: data(rows) x rec(cols); 8b x 16rp x 4mh
        int b = bid >> 6, rp = (bid >> 2) & 15, mh = bid & 3;
        rvec = RV_BASE + (b * N8K + rp * 512) * 8;
        cvec = CR_BASE + (b * N2K + mh * 512) * 8;
        rowTab = D1_BASE + b * N8K + rp * 512;
        colTab = D2_BASE + b * N2K + mh * 512;
    } else {                // P: dataseg x recpseg; 32bp x 4rq x 4mh
        int j = bid - 512, bp = j >> 4, rq = (j >> 2) & 3, mh = j & 3;
        int b = bp >> 2, p = bp & 3;
        rvec = RV_BASE + (b * N8K + p * N2K + rq * 512) * 8;
        cvec = CP_BASE + (b * N8K + p * N2K + mh * 512) * 8;
        rowTab = P1_BASE + b * N8K + p * N2K + rq * 512;
        colTab = P2_BASE + b * N8K + p * N2K + mh * 512;
    }

    // stage 512 col-vecs into LDS (2 x uint4 data + 1 x uint4 ZERO tail
    // per point, stride 12 u32) — tail init makes the unguarded read safe
    {
        const uint4* src = (const uint4*)(ws + cvec);
        const uint4 z4 = make_uint4(0, 0, 0, 0);
        for (int pt = tid; pt < 512; pt += THREADS) {
            uint4 w0 = src[pt * 2], w1 = src[pt * 2 + 1];
            unsigned int* dst = sB + pt * 12;
            *(uint4*)dst = w0;
            *(uint4*)(dst + 4) = w1;
            *(uint4*)(dst + 8) = z4;
        }
        if (tid < 4) sB[512 * 12 + tid] = 0;   // zero the pad
    }

    const char* base = (const char*)ws;
    const bf16x8 zero8 = {0, 0, 0, 0, 0, 0, 0, 0};
    const f32x4 zacc = {0.f, 0.f, 0.f, 0.f};

    // A-frags: 8 row-panels of 16; lane supplies A[row=rln][k=g*8+e]
    bf16x8 afr[8];
    #pragma unroll
    for (int p = 0; p < 8; ++p) {
        int row = wv * 128 + p * 16 + rln;
        afr[p] = (g < 2)
            ? *(const bf16x8*)(base + (size_t)(rvec + row * 8) * 4 + g * 16)
            : zero8;
    }
    float rm[8][4];
    #pragma unroll
    for (int p = 0; p < 8; ++p) {
        rm[p][0] = 3.4e38f; rm[p][1] = 3.4e38f;
        rm[p][2] = 3.4e38f; rm[p][3] = 3.4e38f;
    }

    __syncthreads();

    unsigned int* mins = ws;

    #pragma unroll 1
    for (int half = 0; half < 2; ++half) {
        #pragma unroll 2
        for (int tt = 0; tt < 16; ++tt) {
            const int t = half * 16 + tt;
            // unguarded: g=2 reads zero tail, g=3 reads next record (finite)
            bf16x8 bu = *(const bf16x8*)((const char*)sB + (t * 16 + rln) * 48 + g * 16);
            f32x4 d[8];
            __builtin_amdgcn_s_setprio(1);
            #pragma unroll
            for (int p = 0; p < 8; ++p)
                d[p] = __builtin_amdgcn_mfma_f32_16x16x32_bf16(afr[p], bu, zacc, 0, 0, 0);
            __builtin_amdgcn_s_setprio(0);
            float mp[8];
            #pragma unroll
            for (int p = 0; p < 8; ++p) {
                rm[p][0] = fminf(rm[p][0], d[p][0]);
                rm[p][1] = fminf(rm[p][1], d[p][1]);
                rm[p][2] = fminf(rm[p][2], d[p][2]);
                rm[p][3] = fminf(rm[p][3], d[p][3]);
                mp[p] = fminf(fminf(d[p][0], d[p][1]), fminf(d[p][2], d[p][3]));
            }
            // tree reduce (depth ~2 min3 levels), not an 8-deep chain
            float l0 = min3f(mp[0], mp[1], mp[2]);
            float l1 = min3f(mp[3], mp[4], mp[5]);
            float l2 = min3f(mp[6], mp[7], l0);
            cT[wv][tt * 16 + rln][g] = fminf(l1, l2);
        }
        __syncthreads();
        // merge: 256 threads x 256 local cols; min over 4 waves x 4 g
        {
            float4 q0 = *(const float4*)&cT[0][tid][0];
            float4 q1 = *(const float4*)&cT[1][tid][0];
            float4 q2 = *(const float4*)&cT[2][tid][0];
            float4 q3 = *(const float4*)&cT[3][tid][0];
            float v = fminf(fminf(fminf(q0.x, q0.y), fminf(q0.z, q0.w)),
                            fminf(fminf(q1.x, q1.y), fminf(q1.z, q1.w)));
            v = fminf(v, fminf(fminf(q2.x, q2.y), fminf(q2.z, q2.w)));
            v = fminf(v, fminf(fminf(q3.x, q3.y), fminf(q3.z, q3.w)));
            atomicMin(&mins[colTab + half * 256 + tid], fkey(v));
        }
        __syncthreads();
    }

    // row-mins: reduce across 16 col-lanes (xor 1,2,4,8), one atomic per row
    #pragma unroll
    for (int p = 0; p < 8; ++p) {
        #pragma unroll
        for (int q = 0; q < 4; ++q) {
            float v = rm[p][q];
            v = fminf(v, __shfl_xor(v, 1, 64));
            v = fminf(v, __shfl_xor(v, 2, 64));
            v = fminf(v, __shfl_xor(v, 4, 64));
            v = fminf(v, __shfl_xor(v, 8, 64));
            if (rln == 0)
                atomicMin(&mins[rowTab + wv * 128 + p * 16 + g * 4 + q], fkey(v));
        }
    }
}

__global__ __launch_bounds__(THREADS) void finalize1_kernel(
    const unsigned int* __restrict__ mins, float* __restrict__ part)
{
    __shared__ float sred[4];
    const int blk = blockIdx.x;        // 208 blocks x 1024 entries
    const int tid = threadIdx.x;

    float s = 0.f;
    #pragma unroll
    for (int i = 0; i < 4; ++i) {
        int idx = blk * 1024 + i * THREADS + tid;
        unsigned int k = mins[idx];
        unsigned int bu = (k & 0x80000000u) ? (k & 0x7FFFFFFFu) : ~k;
        float v = __uint_as_float(bu);
        float w = (idx < 65536) ? (1.f / 65536.f) : (1.f / 16384.f);
        s += v * w;
    }
    #pragma unroll
    for (int o = 32; o > 0; o >>= 1) s += __shfl_down(s, o, 64);
    const int lane = tid & 63, wid = tid >> 6;
    if (lane == 0) sred[wid] = s;
    __syncthreads();
    if (tid == 0)
        part[blk] = (sred[0] + sred[1]) + (sred[2] + sred[3]);
}

__global__ __launch_bounds__(THREADS) void finalize2_kernel(
    const float* __restrict__ part, float* __restrict__ out)
{
    __shared__ float sred[4];
    const int tid = threadIdx.x;
    float s = (tid < 208) ? part[tid] : 0.f;
    #pragma unroll
    for (int o = 32; o > 0; o >>= 1) s += __shfl_down(s, o, 64);
    const int lane = tid & 63, wid = tid >> 6;
    if (lane == 0) sred[wid] = s;
    __syncthreads();
    if (tid == 0)
        out[0] = ((sred[0] + sred[1]) + (sred[2] + sred[3])) * 0.2f;  // /5
}

extern "C" void kernel_launch(void* const* d_in, const int* in_sizes, int n_in,
                              void* d_out, int out_size, void* d_ws, size_t ws_size,
                              hipStream_t stream) {
    const float* data = (const float*)d_in[0];
    const float* rec  = (const float*)d_in[1];
    const float* recp = (const float*)d_in[2];
    float* out = (float*)d_out;
    unsigned int* ws = (unsigned int*)d_ws;
    float* part = (float*)d_ws + PART_BASE;

    prep_kernel<<<576, THREADS, 0, stream>>>(data, rec, recp, ws);
    mfma_chamfer_kernel<<<1024, THREADS, 0, stream>>>(ws);
    finalize1_kernel<<<208, THREADS, 0, stream>>>(ws, part);
    finalize2_kernel<<<1, THREADS, 0, stream>>>(part, out);
}

// Round 20
// 47.834 us; speedup vs baseline: 1.2215x; 1.0786x over previous
//
#include <hip/hip_runtime.h>

// Chamfer via MFMA (math verified exact in R11/R12): d[n,m] = na + nb - 2 a.b
// as ONE bf16 MFMA (16x16x32) per 16x16 tile, 13-slot K packing w/ hi/lo:
//   k 0-2: ah*(-2bh)  k 3-5: ah*(-2bl)  k 6-8: al*(-2bh)
//   k 9,10: nah,nal * 1   k 11,12: 1 * nbh,nbl   k>=13: zero (g>=2 lanes)
// Each matrix computed ONCE: row-mins -> d1/p1, col-mins -> d2/p2.
// R14 schedule (measured best of R11-R19): t-loop has NO cross-lane ops and
// NO long-lived reg arrays. Per-lane col partial -> one ds_write_b32 into
// cT[wave][col][g] (16 KB); two halves of 16 t each; per-half merge (min
// over 16 slots) + 1 atomic per col. Row mins via width-16 shfl tree.
// LDS = 24 KB sB + 16 KB cT = 40 KB (4 blk/CU). atomicMin monotone-key
// table (exact, order-independent -> deterministic); 0xFF init fused in prep.

#define N2K 2048
#define N8K 8192
#define THREADS 256

// ws u32 layout:
#define D1_BASE 0          // d1: b*8192+a
#define D2_BASE 65536      // d2: b*2048+a
#define P1_BASE 81920      // p1: b*8192+p*2048+a
#define P2_BASE 147456     // p2: b*8192+p*2048+a
#define NMINS 212992
#define PART_BASE 212992   // 208 floats
#define RV_BASE 213504     // data row-vecs : 65536 pts x 8 u32 (32B)
#define CR_BASE 737792     // rec  col-vecs : 16384 pts x 8 u32
#define CP_BASE 868864     // recp col-vecs : 65536 pts x 8 u32  (end 1393152)

typedef short bf16x8 __attribute__((ext_vector_type(8)));
typedef float f32x4 __attribute__((ext_vector_type(4)));

__device__ __forceinline__ float min3f(float a, float b, float c) {
    float d;
    asm("v_min3_f32 %0, %1, %2, %3" : "=v"(d) : "v"(a), "v"(b), "v"(c));
    return d;
}
__device__ __forceinline__ unsigned int fkey(float v) {
    unsigned int u = __float_as_uint(v);
    return (u & 0x80000000u) ? ~u : (u | 0x80000000u);
}
__device__ __forceinline__ unsigned short bf16rne(float f) {
    unsigned int u = __float_as_uint(f);
    return (unsigned short)((u + 0x7FFFu + ((u >> 16) & 1u)) >> 16);
}
__device__ __forceinline__ float bf2f(unsigned short s) {
    return __uint_as_float(((unsigned int)s) << 16);
}

__global__ __launch_bounds__(THREADS) void prep_kernel(
    const float* __restrict__ data, const float* __restrict__ rec,
    const float* __restrict__ recp, unsigned int* __restrict__ ws)
{
    const int idx = blockIdx.x * THREADS + threadIdx.x;   // 0..147455

    // fused min-table init (replaces hipMemsetAsync): [0, NMINS) <- 0xFF..
    if (idx < NMINS) ws[idx] = 0xFFFFFFFFu;
    if (idx + 147456 < NMINS) ws[idx + 147456] = 0xFFFFFFFFu;

    float x, y, z; int out; int isrow;
    if (idx < 65536) {                       // data -> row vectors
        int b = idx >> 13, i = idx & 8191;
        const float* p = data + b * 3 * N8K;
        x = p[i]; y = p[N8K + i]; z = p[2 * N8K + i];
        out = RV_BASE + idx * 8; isrow = 1;
    } else if (idx < 81920) {                // rec -> col vectors
        int j = idx - 65536; int b = j >> 11, i = j & 2047;
        const float* p = rec + b * 3 * N2K;
        x = p[i]; y = p[N2K + i]; z = p[2 * N2K + i];
        out = CR_BASE + j * 8; isrow = 0;
    } else {                                 // recp -> col vectors
        int j = idx - 81920; int b = j >> 13, i = j & 8191;
        const float* p = recp + b * 3 * N8K;
        x = p[i]; y = p[N8K + i]; z = p[2 * N8K + i];
        out = CP_BASE + j * 8; isrow = 0;
    }
    unsigned short xh = bf16rne(x), yh = bf16rne(y), zh = bf16rne(z);
    unsigned short xl = bf16rne(x - bf2f(xh));
    unsigned short yl = bf16rne(y - bf2f(yh));
    unsigned short zl = bf16rne(z - bf2f(zh));
    float na = x * x + y * y + z * z;
    unsigned short nh = bf16rne(na);
    unsigned short nl = bf16rne(na - bf2f(nh));
    const unsigned short ONE = 0x3F80u;
    unsigned short s[16];
    if (isrow) {
        s[0]=xh; s[1]=yh; s[2]=zh;  s[3]=xh; s[4]=yh; s[5]=zh;
        s[6]=xl; s[7]=yl; s[8]=zl;  s[9]=nh; s[10]=nl;
        s[11]=ONE; s[12]=ONE; s[13]=0; s[14]=0; s[15]=0;
    } else {
        unsigned short m2xh = bf16rne(-2.f * bf2f(xh));
        unsigned short m2yh = bf16rne(-2.f * bf2f(yh));
        unsigned short m2zh = bf16rne(-2.f * bf2f(zh));
        unsigned short m2xl = bf16rne(-2.f * bf2f(xl));
        unsigned short m2yl = bf16rne(-2.f * bf2f(yl));
        unsigned short m2zl = bf16rne(-2.f * bf2f(zl));
        s[0]=m2xh; s[1]=m2yh; s[2]=m2zh;  s[3]=m2xl; s[4]=m2yl; s[5]=m2zl;
        s[6]=m2xh; s[7]=m2yh; s[8]=m2zh;  s[9]=ONE; s[10]=ONE;
        s[11]=nh; s[12]=nl; s[13]=0; s[14]=0; s[15]=0;
    }
    uint4 w0, w1;
    w0.x = (unsigned)s[0]  | ((unsigned)s[1]  << 16);
    w0.y = (unsigned)s[2]  | ((unsigned)s[3]  << 16);
    w0.z = (unsigned)s[4]  | ((unsigned)s[5]  << 16);
    w0.w = (unsigned)s[6]  | ((unsigned)s[7]  << 16);
    w1.x = (unsigned)s[8]  | ((unsigned)s[9]  << 16);
    w1.y = (unsigned)s[10] | ((unsigned)s[11] << 16);
    w1.z = (unsigned)s[12] | ((unsigned)s[13] << 16);
    w1.w = (unsigned)s[14] | ((unsigned)s[15] << 16);
    uint4* dst = (uint4*)(ws + out);
    dst[0] = w0; dst[1] = w1;
}

__global__ __launch_bounds__(THREADS) void mfma_chamfer_kernel(unsigned int* ws)
{
    __shared__ unsigned int sB[512 * 12];   // col-vecs, 48B stride (24 KB)
    __shared__ float cT[4][256][4];         // [wave][col_local][g] (16 KB)

    const int tid = threadIdx.x, lane = tid & 63, wv = tid >> 6;
    const int g = lane >> 4, rln = lane & 15;
    const int bid = blockIdx.x;             // 1024 blocks

    int rvec, cvec, rowTab, colTab;
    if (bid < 512) {        // G: data(rows) x rec(cols); 8b x 16rp x 4mh
        int b = bid >> 6, rp = (bid >> 2) & 15, mh = bid & 3;
        rvec = RV_BASE + (b * N8K + rp * 512) * 8;
        cvec = CR_BASE + (b * N2K + mh * 512) * 8;
        rowTab = D1_BASE + b * N8K + rp * 512;
        colTab = D2_BASE + b * N2K + mh * 512;
    } else {                // P: dataseg x recpseg; 32bp x 4rq x 4mh
        int j = bid - 512, bp = j >> 4, rq = (j >> 2) & 3, mh = j & 3;
        int b = bp >> 2, p = bp & 3;
        rvec = RV_BASE + (b * N8K + p * N2K + rq * 512) * 8;
        cvec = CP_BASE + (b * N8K + p * N2K + mh * 512) * 8;
        rowTab = P1_BASE + b * N8K + p * N2K + rq * 512;
        colTab = P2_BASE + b * N8K + p * N2K + mh * 512;
    }

    // stage 512 col-vecs into LDS (2 x uint4 per point, stride 12 u32)
    {
        const uint4* src = (const uint4*)(ws + cvec);
        for (int pt = tid; pt < 512; pt += THREADS) {
            uint4 w0 = src[pt * 2], w1 = src[pt * 2 + 1];
            unsigned int* dst = sB + pt * 12;
            *(uint4*)dst = w0;
            *(uint4*)(dst + 4) = w1;
        }
    }

    const char* base = (const char*)ws;
    const bf16x8 zero8 = {0, 0, 0, 0, 0, 0, 0, 0};
    const f32x4 zacc = {0.f, 0.f, 0.f, 0.f};

    // A-frags: 8 row-panels of 16; lane supplies A[row=rln][k=g*8+e]
    bf16x8 afr[8];
    #pragma unroll
    for (int p = 0; p < 8; ++p) {
        int row = wv * 128 + p * 16 + rln;
        afr[p] = (g < 2)
            ? *(const bf16x8*)(base + (size_t)(rvec + row * 8) * 4 + g * 16)
            : zero8;
    }
    float rm[8][4];
    #pragma unroll
    for (int p = 0; p < 8; ++p) {
        rm[p][0] = 3.4e38f; rm[p][1] = 3.4e38f;
        rm[p][2] = 3.4e38f; rm[p][3] = 3.4e38f;
    }

    __syncthreads();

    unsigned int* mins = ws;

    #pragma unroll 1
    for (int half = 0; half < 2; ++half) {
        #pragma unroll 2
        for (int tt = 0; tt < 16; ++tt) {
            const int t = half * 16 + tt;
            bf16x8 bu = zero8;
            if (g < 2)
                bu = *(const bf16x8*)((const char*)sB + (t * 16 + rln) * 48 + g * 16);
            f32x4 d[8];
            #pragma unroll
            for (int p = 0; p < 8; ++p)
                d[p] = __builtin_amdgcn_mfma_f32_16x16x32_bf16(afr[p], bu, zacc, 0, 0, 0);
            float cmt = 3.4e38f;
            #pragma unroll
            for (int p = 0; p < 8; ++p) {
                rm[p][0] = fminf(rm[p][0], d[p][0]);
                rm[p][1] = fminf(rm[p][1], d[p][1]);
                rm[p][2] = fminf(rm[p][2], d[p][2]);
                rm[p][3] = fminf(rm[p][3], d[p][3]);
                float w = min3f(d[p][1], d[p][2], d[p][3]);   // indep per p
                cmt = min3f(cmt, d[p][0], w);                 // 8-deep chain
            }
            cT[wv][tt * 16 + rln][g] = cmt;    // unique slot, no conflicts
        }
        __syncthreads();
        // merge: 256 threads x 256 local cols; min over 4 waves x 4 g
        {
            float4 q0 = *(const float4*)&cT[0][tid][0];
            float4 q1 = *(const float4*)&cT[1][tid][0];
            float4 q2 = *(const float4*)&cT[2][tid][0];
            float4 q3 = *(const float4*)&cT[3][tid][0];
            float v = fminf(fminf(fminf(q0.x, q0.y), fminf(q0.z, q0.w)),
                            fminf(fminf(q1.x, q1.y), fminf(q1.z, q1.w)));
            v = fminf(v, fminf(fminf(q2.x, q2.y), fminf(q2.z, q2.w)));
            v = fminf(v, fminf(fminf(q3.x, q3.y), fminf(q3.z, q3.w)));
            atomicMin(&mins[colTab + half * 256 + tid], fkey(v));
        }
        __syncthreads();
    }

    // row-mins: reduce across 16 col-lanes (xor 1,2,4,8), one atomic per row
    #pragma unroll
    for (int p = 0; p < 8; ++p) {
        #pragma unroll
        for (int q = 0; q < 4; ++q) {
            float v = rm[p][q];
            v = fminf(v, __shfl_xor(v, 1, 64));
            v = fminf(v, __shfl_xor(v, 2, 64));
            v = fminf(v, __shfl_xor(v, 4, 64));
            v = fminf(v, __shfl_xor(v, 8, 64));
            if (rln == 0)
                atomicMin(&mins[rowTab + wv * 128 + p * 16 + g * 4 + q], fkey(v));
        }
    }
}

__global__ __launch_bounds__(THREADS) void finalize1_kernel(
    const unsigned int* __restrict__ mins, float* __restrict__ part)
{
    __shared__ float sred[4];
    const int blk = blockIdx.x;        // 208 blocks x 1024 entries
    const int tid = threadIdx.x;

    float s = 0.f;
    #pragma unroll
    for (int i = 0; i < 4; ++i) {
        int idx = blk * 1024 + i * THREADS + tid;
        unsigned int k = mins[idx];
        unsigned int bu = (k & 0x80000000u) ? (k & 0x7FFFFFFFu) : ~k;
        float v = __uint_as_float(bu);
        float w = (idx < 65536) ? (1.f / 65536.f) : (1.f / 16384.f);
        s += v * w;
    }
    #pragma unroll
    for (int o = 32; o > 0; o >>= 1) s += __shfl_down(s, o, 64);
    const int lane = tid & 63, wid = tid >> 6;
    if (lane == 0) sred[wid] = s;
    __syncthreads();
    if (tid == 0)
        part[blk] = (sred[0] + sred[1]) + (sred[2] + sred[3]);
}

__global__ __launch_bounds__(THREADS) void finalize2_kernel(
    const float* __restrict__ part, float* __restrict__ out)
{
    __shared__ float sred[4];
    const int tid = threadIdx.x;
    float s = (tid < 208) ? part[tid] : 0.f;
    #pragma unroll
    for (int o = 32; o > 0; o >>= 1) s += __shfl_down(s, o, 64);
    const int lane = tid & 63, wid = tid >> 6;
    if (lane == 0) sred[wid] = s;
    __syncthreads();
    if (tid == 0)
        out[0] = ((sred[0] + sred[1]) + (sred[2] + sred[3])) * 0.2f;  // /5
}

extern "C" void kernel_launch(void* const* d_in, const int* in_sizes, int n_in,
                              void* d_out, int out_size, void* d_ws, size_t ws_size,
                              hipStream_t stream) {
    const float* data = (const float*)d_in[0];
    const float* rec  = (const float*)d_in[1];
    const float* recp = (const float*)d_in[2];
    float* out = (float*)d_out;
    unsigned int* ws = (unsigned int*)d_ws;
    float* part = (float*)d_ws + PART_BASE;

    prep_kernel<<<576, THREADS, 0, stream>>>(data, rec, recp, ws);
    mfma_chamfer_kernel<<<1024, THREADS, 0, stream>>>(ws);
    finalize1_kernel<<<208, THREADS, 0, stream>>>(ws, part);
    finalize2_kernel<<<1, THREADS, 0, stream>>>(part, out);
}